// Round 1
// baseline (304.377 us; speedup 1.0000x reference)
//
#include <hip/hip_runtime.h>
#include <hip/hip_bf16.h>

typedef __attribute__((ext_vector_type(8))) short short8;
typedef __attribute__((ext_vector_type(4))) float float4v;

#define N_PTS 8192
#define DIM   128
#define BM    128

__device__ __forceinline__ unsigned short f2bf(float f) {
    unsigned u = __builtin_bit_cast(unsigned, f);
    u += 0x7fffu + ((u >> 16) & 1u);          // RNE to bf16
    return (unsigned short)(u >> 16);
}
__device__ __forceinline__ float bf2f(unsigned short h) {
    unsigned u = ((unsigned)h) << 16;
    return __builtin_bit_cast(float, u);
}

__global__ __launch_bounds__(256, 2)
void fsim_kernel(const float* __restrict__ F, float* __restrict__ out) {
    // 64 KB total LDS -> 2 blocks/CU. XOR-swizzled bf16 tiles (no padding needed).
    __shared__ short As[BM * DIM];
    __shared__ short Bs[BM * DIM];

    const int t    = threadIdx.x;
    const int brow = blockIdx.y;
    const int bcol = blockIdx.x;

    // ---- stage: fp32 -> bf16 into swizzled LDS; per-row sq from the SAME
    // bf16-rounded values (keeps the diagonal at ~0 after clamp) ----
    const int r    = t & 127;
    const int isB  = t >> 7;                  // threads 0..127 -> A rows, 128..255 -> B rows
    const int grow = (isB ? bcol : brow) * BM + r;
    const float* __restrict__ src = F + (size_t)grow * DIM;
    short* dst = isB ? Bs : As;
    float s = 0.f;
#pragma unroll
    for (int i = 0; i < 16; ++i) {            // 16 granules of 8 floats = one row
        float4v f0 = *(const float4v*)(src + i * 8);
        float4v f1 = *(const float4v*)(src + i * 8 + 4);
        short8 p;
#pragma unroll
        for (int k = 0; k < 4; ++k) {
            unsigned short b0 = f2bf(f0[k]);
            unsigned short b1 = f2bf(f1[k]);
            p[k]     = (short)b0;
            p[k + 4] = (short)b1;
            float v0 = bf2f(b0), v1 = bf2f(b1);
            s += v0 * v0 + v1 * v1;
        }
        // XOR swizzle: granule i of row r lands at phys granule i^(r&15).
        // Bank-optimal for both ds_write_b128 here and ds_read_b128 below.
        const int pg = (i ^ (r & 15)) * 8;
        *(short8*)(dst + r * DIM + pg) = p;
    }
    __syncthreads();

    // ---- MFMA k-loop: C = Fb * Fb^T on the 128x128 tile, K=128 in 4 steps ----
    const int lane = t & 63;
    const int w    = t >> 6;
    const int wr   = (w >> 1) * 64;           // wave quadrant: rows
    const int wc   = (w & 1) * 64;            // wave quadrant: cols
    const int lrow = lane & 15;
    const int quad = lane >> 4;

    float4v acc[4][4];
#pragma unroll
    for (int a = 0; a < 4; ++a)
#pragma unroll
        for (int b = 0; b < 4; ++b)
            acc[a][b] = (float4v){0.f, 0.f, 0.f, 0.f};

#pragma unroll
    for (int ks = 0; ks < 4; ++ks) {
        short8 af[4], bfv[4];
        const int g = ks * 4 + quad;          // logical 8-elem granule along K
#pragma unroll
        for (int mt = 0; mt < 4; ++mt) {
            const int row = wr + mt * 16 + lrow;
            af[mt] = *(const short8*)(As + row * DIM + ((g ^ (row & 15)) * 8));
        }
#pragma unroll
        for (int nt = 0; nt < 4; ++nt) {
            const int row = wc + nt * 16 + lrow;
            bfv[nt] = *(const short8*)(Bs + row * DIM + ((g ^ (row & 15)) * 8));
        }
#pragma unroll
        for (int mt = 0; mt < 4; ++mt)
#pragma unroll
            for (int nt = 0; nt < 4; ++nt)
                acc[mt][nt] = __builtin_amdgcn_mfma_f32_16x16x32_bf16(
                    af[mt], bfv[nt], acc[mt][nt], 0, 0, 0);
    }

    // ---- publish sq (reuse As space; sqf[t] == (isB*128 + r)) ----
    __syncthreads();                          // all frag reads of As/Bs done
    float* sqf = (float*)As;
    sqf[t] = s;                               // [0..127]=A rows, [128..255]=B rows
    __syncthreads();

    // ---- epilogue: -sqrt(max(0, sq_r + sq_c - 2*gram)) ----
    const size_t orow0    = (size_t)brow * BM;
    const int    col_base = bcol * BM;
#pragma unroll
    for (int mt = 0; mt < 4; ++mt) {
#pragma unroll
        for (int nt = 0; nt < 4; ++nt) {
            const int n   = wc + nt * 16 + lrow;
            const float sc = sqf[128 + n];
            const int col = col_base + n;
#pragma unroll
            for (int reg = 0; reg < 4; ++reg) {
                const int m  = wr + mt * 16 + quad * 4 + reg;   // C/D layout: row=(lane>>4)*4+reg, col=lane&15
                const float sr = sqf[m];
                float d2 = sr + sc - 2.0f * acc[mt][nt][reg];
                d2 = d2 > 0.f ? d2 : 0.f;
                out[(orow0 + m) * (size_t)N_PTS + col] = -__builtin_sqrtf(d2);
            }
        }
    }
}

extern "C" void kernel_launch(void* const* d_in, const int* in_sizes, int n_in,
                              void* d_out, int out_size, void* d_ws, size_t ws_size,
                              hipStream_t stream) {
    const float* F = (const float*)d_in[0];
    float* out = (float*)d_out;
    dim3 grid(N_PTS / BM, N_PTS / BM);        // 64 x 64
    fsim_kernel<<<grid, 256, 0, stream>>>(F, out);
}

// Round 2
// 273.051 us; speedup vs baseline: 1.1147x; 1.1147x over previous
//
#include <hip/hip_runtime.h>
#include <hip/hip_bf16.h>

typedef __attribute__((ext_vector_type(8))) short short8;
typedef __attribute__((ext_vector_type(4))) float float4v;

#define N_PTS 8192
#define DIM   128
#define BM    128

typedef const __attribute__((address_space(1))) void* gptr_t;
typedef __attribute__((address_space(3))) void* lptr_t;

__device__ __forceinline__ unsigned short f2bf(float f) {
    unsigned u = __builtin_bit_cast(unsigned, f);
    u += 0x7fffu + ((u >> 16) & 1u);          // RNE to bf16
    return (unsigned short)(u >> 16);
}
__device__ __forceinline__ float bf2f(unsigned short h) {
    unsigned u = ((unsigned)h) << 16;
    return __builtin_bit_cast(float, u);
}

// ---- pre-pass: fp32 -> bf16 once, XOR-swizzled granules, plus per-row sq ----
// Swizzle: granule g (8 bf16) of row r lands at granule g^(r&15). The main
// kernel's LDS staging is then a pure linear DMA and the k-loop reads land
// bank-spread. sq is computed from the SAME bf16-rounded values so the
// diagonal of d2 stays ~0 after clamping.
__global__ __launch_bounds__(128)
void prep_kernel(const float* __restrict__ F,
                 unsigned short* __restrict__ bfF,
                 float* __restrict__ sqg) {
    const int row = blockIdx.x * 128 + threadIdx.x;   // 64 blocks x 128 = 8192 rows
    const float* __restrict__ src = F + (size_t)row * DIM;
    unsigned short* dst = bfF + (size_t)row * DIM;
    float s = 0.f;
#pragma unroll
    for (int g = 0; g < 16; ++g) {
        float4v f0 = *(const float4v*)(src + g * 8);
        float4v f1 = *(const float4v*)(src + g * 8 + 4);
        short8 p;
#pragma unroll
        for (int k = 0; k < 4; ++k) {
            unsigned short b0 = f2bf(f0[k]);
            unsigned short b1 = f2bf(f1[k]);
            p[k]     = (short)b0;
            p[k + 4] = (short)b1;
            float v0 = bf2f(b0), v1 = bf2f(b1);
            s += v0 * v0 + v1 * v1;
        }
        *(short8*)(dst + (g ^ (row & 15)) * 8) = p;
    }
    sqg[row] = s;
}

// ---- main: 128x128 output tile per block, bf16 MFMA, DMA staging ----
__global__ __launch_bounds__(256, 2)
void fsim_kernel(const unsigned short* __restrict__ bfF,
                 const float* __restrict__ sqg,
                 float* __restrict__ out) {
    __shared__ unsigned short As[BM * DIM];   // 32 KB (swizzled bf16)
    __shared__ unsigned short Bs[BM * DIM];   // 32 KB
    __shared__ float sqA[BM];
    __shared__ float sqB[BM];

    const int t    = threadIdx.x;
    const int lane = t & 63;
    const int w    = t >> 6;
    const int brow = blockIdx.y;
    const int bcol = blockIdx.x;

    // ---- stage: linear global->LDS DMA, 16 B/lane, zero VALU conversion ----
    const char* gA = (const char*)(bfF + (size_t)brow * BM * DIM);
    const char* gB = (const char*)(bfF + (size_t)bcol * BM * DIM);
    char* lA = (char*)As;
    char* lB = (char*)Bs;
    const int off = w * 8192 + lane * 16;     // each wave copies 8 KB per tile
#pragma unroll
    for (int i = 0; i < 8; ++i) {
        __builtin_amdgcn_global_load_lds((gptr_t)(gA + off + i * 1024),
                                         (lptr_t)(lA + off + i * 1024), 16, 0, 0);
        __builtin_amdgcn_global_load_lds((gptr_t)(gB + off + i * 1024),
                                         (lptr_t)(lB + off + i * 1024), 16, 0, 0);
    }
    // sq rows for this tile (L2-hot, 1 KB total)
    if (t < 128) sqA[t] = sqg[brow * BM + t];
    else         sqB[t - 128] = sqg[bcol * BM + (t - 128)];
    __syncthreads();                          // compiler drains vmcnt here

    // ---- MFMA k-loop: gram = Fb * Fb^T, K=128 in 4 steps ----
    const int wr   = (w >> 1) * 64;
    const int wc   = (w & 1) * 64;
    const int lrow = lane & 15;
    const int quad = lane >> 4;

    float4v acc[4][4];
#pragma unroll
    for (int a = 0; a < 4; ++a)
#pragma unroll
        for (int b = 0; b < 4; ++b)
            acc[a][b] = (float4v){0.f, 0.f, 0.f, 0.f};

#pragma unroll
    for (int ks = 0; ks < 4; ++ks) {
        short8 af[4], bfv[4];
        const int g = ks * 4 + quad;          // logical granule along K
#pragma unroll
        for (int mt = 0; mt < 4; ++mt) {
            const int row = wr + mt * 16 + lrow;
            af[mt] = *(const short8*)((const short*)As + row * DIM + ((g ^ (row & 15)) * 8));
        }
#pragma unroll
        for (int nt = 0; nt < 4; ++nt) {
            const int row = wc + nt * 16 + lrow;
            bfv[nt] = *(const short8*)((const short*)Bs + row * DIM + ((g ^ (row & 15)) * 8));
        }
#pragma unroll
        for (int mt = 0; mt < 4; ++mt)
#pragma unroll
            for (int nt = 0; nt < 4; ++nt)
                acc[mt][nt] = __builtin_amdgcn_mfma_f32_16x16x32_bf16(
                    af[mt], bfv[nt], acc[mt][nt], 0, 0, 0);
    }

    // ---- epilogue: -sqrt(max(0, sq_r + sq_c - 2*gram)) ----
    // nt innermost: each thread fills 4 rows x 256 B contiguously -> L2 merge.
    const size_t orow0    = (size_t)brow * BM;
    const int    col_base = bcol * BM;
    float scb[4];
#pragma unroll
    for (int nt = 0; nt < 4; ++nt) scb[nt] = sqB[wc + nt * 16 + lrow];
#pragma unroll
    for (int mt = 0; mt < 4; ++mt) {
#pragma unroll
        for (int reg = 0; reg < 4; ++reg) {
            const int m  = wr + mt * 16 + quad * 4 + reg;  // C/D: row=(lane>>4)*4+reg, col=lane&15
            const float sr = sqA[m];
            float* orow = out + (orow0 + m) * (size_t)N_PTS + col_base;
#pragma unroll
            for (int nt = 0; nt < 4; ++nt) {
                const int n = wc + nt * 16 + lrow;
                float d2 = sr + scb[nt] - 2.0f * acc[mt][nt][reg];
                d2 = d2 > 0.f ? d2 : 0.f;
                orow[n] = -__builtin_sqrtf(d2);
            }
        }
    }
}

extern "C" void kernel_launch(void* const* d_in, const int* in_sizes, int n_in,
                              void* d_out, int out_size, void* d_ws, size_t ws_size,
                              hipStream_t stream) {
    const float* F = (const float*)d_in[0];
    float* out = (float*)d_out;
    unsigned short* bfF = (unsigned short*)d_ws;                       // 2 MB bf16
    float* sqg = (float*)((char*)d_ws + (size_t)N_PTS * DIM * 2);      // +32 KB sq

    prep_kernel<<<dim3(N_PTS / 128), 128, 0, stream>>>(F, bfF, sqg);
    dim3 grid(N_PTS / BM, N_PTS / BM);        // 64 x 64
    fsim_kernel<<<grid, 256, 0, stream>>>(bfF, sqg, out);
}